// Round 15
// baseline (238.141 us; speedup 1.0000x reference)
//
#include <hip/hip_runtime.h>
#include <math.h>

// infoFSM mask-scorer MLP — Round 14: TM=64 main (spill-safe) + R13 tail.
//
// R13 post-mortem (WIN 248->236): fix pass ~30us; main 167us now dominates.
// Counter audit: L2 weight stream 49us + HBM 44us + VALU 53us + MFMA 23us
// SUM to ~167 -> phases don't overlap; biggest removable term is weight L2
// (scales 1/TM). R9's TM=64 spill is now explained: unroll-4 fragment
// liveness (64 regs) + 4x16 acc chains in GEMM2 breached the 128 cap.
// R14: TM=64 with SINGLE acc set per GEMM (64/32/16 regs), unroll 2 only
// -> peak ~115 regs < 128 @ launch_bounds(512,4), 2 blocks/CU (LDS 64.3KB).
// Weight L2 halves (49->25us); 2x MFMA per B-load. Layouts = R9's verified
// TM=64 code. prep/fix_rows byte-identical to R13.
// Numerics: fp16 single-term, BAND=2e-3 (~22sigma), exact fp32 fix pass.

namespace {

constexpr int R_ROWS = 128 * 512;   // 65536
constexpr int D0 = 512, D1 = 512, D2 = 256, D3 = 128;
constexpr int TM = 64;              // rows per block (pass B)
constexpr int NT = 512;             // 8 waves

typedef _Float16 vhalf8 __attribute__((ext_vector_type(8)));
typedef _Float16 vhalf4 __attribute__((ext_vector_type(4)));
typedef __attribute__((ext_vector_type(16))) float vf16;
typedef __attribute__((ext_vector_type(4)))  float vf4;

// ---------------- helpers ----------------
__device__ __forceinline__ float gelu_exact(float x) {
    return 0.5f * x * (1.0f + erff(x * 0.70710678118654752440f));
}
// A&S 7.1.26 erf: |abs err| <= 1.5e-7 — far below fp16 path error.
__device__ __forceinline__ float gelu_fast(float x) {
    const float s = fabsf(x) * 0.70710678118654752440f;
    const float t = __builtin_amdgcn_rcpf(fmaf(0.3275911f, s, 1.0f));
    float p = fmaf(1.061405429f, t, -1.453152027f);
    p = fmaf(p, t, 1.421413741f);
    p = fmaf(p, t, -0.284496736f);
    p = fmaf(p, t, 0.254829592f);
    p *= t;
    const float e = __builtin_amdgcn_exp2f(s * s * -1.44269504088896341f);
    float er = fmaf(-p, e, 1.0f);             // erf(|x|/sqrt2)
    er = copysignf(er, x);
    return 0.5f * x * (1.0f + er);
}
__device__ __forceinline__ vf16 vzero16() {
    vf16 v;
    #pragma unroll
    for (int i = 0; i < 16; ++i) v[i] = 0.0f;
    return v;
}
__device__ __forceinline__ vf4 vzero4() {
    vf4 v;
    #pragma unroll
    for (int i = 0; i < 4; ++i) v[i] = 0.0f;
    return v;
}

// LDS activation tiles: [row][k] fp16, XOR-swizzle bits 4..6.
__device__ __forceinline__ int swz_off(int row, int colElem, int pitchB) {
    return (row * pitchB + colElem * 2) ^ ((row & 7) << 4);
}
// 32x32 A-fragment read: row = row0 + lane&31, k = k0 + (lane>>5)*8
__device__ __forceinline__ vhalf8 ld_act32(const char* base, int lane, int pitchB,
                                           int row0, int k0) {
    const int row = row0 + (lane & 31);
    const int k = k0 + ((lane >> 5) << 3);
    return *(const vhalf8*)(base + swz_off(row, k, pitchB));
}
// 16x16 A-fragment read: row = row0 + lane&15, k = k0 + (lane>>4)*8
__device__ __forceinline__ vhalf8 ld_act16(const char* base, int lane, int pitchB,
                                           int row0, int k0) {
    const int row = row0 + (lane & 15);
    const int k = k0 + ((lane >> 4) << 3);
    return *(const vhalf8*)(base + swz_off(row, k, pitchB));
}
// packed weight fragment: P + blk*1024B + lane*16B
__device__ __forceinline__ vhalf8 ld_pack(const char* __restrict__ P,
                                          int blk, int lane) {
    return *(const vhalf8*)(P + (((size_t)blk) << 10) + (lane << 4));
}
__device__ __forceinline__ void st_hi(char* base, int row, int col, int pitchB, float x) {
    *(_Float16*)(base + swz_off(row, col, pitchB)) = (_Float16)x;
}

#define MFMA32(a, b, c) __builtin_amdgcn_mfma_f32_32x32x16_f16((a), (b), (c), 0, 0, 0)
#define MFMA16(a, b, c) __builtin_amdgcn_mfma_f32_16x16x32_f16((a), (b), (c), 0, 0, 0)

constexpr float BAND = 2e-3f;   // on v = prob*prev_m; ~22x RMS fp16-path err

// ---------------- pass A: prep weights (pack fp16 frags + fp32 transposes) --
__global__ __launch_bounds__(256) void prep_weights(
    const float* __restrict__ W_L, const float* __restrict__ W_l1,
    const float* __restrict__ W_l2,
    char* __restrict__ P1, char* __restrict__ P2, char* __restrict__ P3,
    float* __restrict__ WT1, float* __restrict__ WT2, float* __restrict__ WT3)
{
    if (blockIdx.x < 208) {
        const int g = blockIdx.x * 256 + threadIdx.x;   // 53248 threads
        const float* src;
        char* dst;
        int e, k, K, blk, lane;
        if (g < 32768) {
            lane = g & 63;
            const int ks = (g >> 6) & 31, nt = g >> 11;
            src = W_L; K = 512; dst = P1;
            e = nt * 32 + (lane & 31);
            k = ks * 16 + ((lane >> 5) << 3);
            blk = nt * 32 + ks;
        } else if (g < 49152) {
            const int h = g - 32768;
            lane = h & 63;
            const int ks = (h >> 6) & 31, nt = h >> 11;
            src = W_l1; K = 512; dst = P2;
            e = nt * 32 + (lane & 31);
            k = ks * 16 + ((lane >> 5) << 3);
            blk = nt * 32 + ks;
        } else {
            const int h = g - 49152;
            lane = h & 63;
            const int ks = (h >> 6) & 7, nt = h >> 9;
            src = W_l2; K = 256; dst = P3;
            e = nt * 16 + (lane & 15);
            k = ks * 32 + ((lane >> 4) << 3);
            blk = nt * 8 + ks;
        }
        const float4 v0 = *(const float4*)&src[(size_t)e * K + k];
        const float4 v1 = *(const float4*)&src[(size_t)e * K + k + 4];
        const float xs[8] = {v0.x, v0.y, v0.z, v0.w, v1.x, v1.y, v1.z, v1.w};
        vhalf8 hv;
        #pragma unroll
        for (int j = 0; j < 8; ++j) hv[j] = (_Float16)xs[j];
        *(vhalf8*)(dst + (((size_t)blk) << 10) + lane * 16) = hv;
    } else {
        const int g = (blockIdx.x - 208) * 256 + threadIdx.x;   // 425984 threads
        if (g < 262144) {
            const int k = g >> 9, e = g & 511;
            WT1[g] = W_L[(size_t)e * 512 + k];
        } else if (g < 393216) {
            const int h = g - 262144;
            const int k = h >> 8, e = h & 255;
            WT2[h] = W_l1[(size_t)e * 512 + k];
        } else {
            const int h = g - 393216;
            const int k = h >> 7, e = h & 127;
            WT3[h] = W_l2[(size_t)e * 256 + k];
        }
    }
}

// ---------------- pass B: fused fp16 MFMA MLP, TM=64, 64.3KB LDS ------------
// LDS overlay (bytes):
//   stage A:  A  [0,64K)  f16 [64][512] pitch 1024
//   GEMM1 ep: X1 [0,64K)  f16 [64][512] pitch 1024  (A dead, B2a)
//   GEMM2 ep: X2 [0,32K)  f16 [64][256] pitch 512   (X1 dead, B3a)
//   GEMM3 ep: X3 [0,33792) f32 [64][132]            (X2 dead, B4a)
//   sM at [65536, 65792)
constexpr int SMEM_BYTES = 65536 + 256;

__global__ __launch_bounds__(NT, 4) void mlp_mfma(
    const float* __restrict__ input, const float* __restrict__ prev_m,
    const float* __restrict__ W_l3,
    const char* __restrict__ P1, const char* __restrict__ P2,
    const char* __restrict__ P3,
    float* __restrict__ out, float* __restrict__ mask_out, float* __restrict__ currm_out,
    unsigned int* __restrict__ ctr, int* __restrict__ list)
{
    __shared__ __attribute__((aligned(16))) char smem[SMEM_BYTES];
    char* A   = smem;                         // then X1, then X2 (overlaid)
    float* sX3 = (float*)smem;                // [64][132] f32 (over X2, post-B4a)
    float* sM  = (float*)(smem + 65536);      // [64]

    const int tid  = threadIdx.x;
    const int lane = tid & 63;
    const int wid  = tid >> 6;
    const int row0 = blockIdx.x * TM;

    // ---- stage A: 64 input rows -> fp16, swizzled ----
    #pragma unroll 4
    for (int i = 0; i < 16; ++i) {
        const int c  = i * NT + tid;           // 0..8191 float4-chunks
        const int r  = c >> 7;                 // 0..63
        const int kq = (c & 127) << 2;
        const float4 v = *(const float4*)&input[(size_t)(row0 + r) * D0 + kq];
        vhalf4 hv = {(_Float16)v.x, (_Float16)v.y, (_Float16)v.z, (_Float16)v.w};
        const int off = (r * 1024 + kq * 2) ^ ((r & 7) << 4);   // 8B-aligned
        *(vhalf4*)(A + off) = hv;
    }
    __syncthreads();   // B1: A staged

    // ---- GEMM1: X1 = gelu(A @ W_L^T), 64x512, K=512, 32x32x16 ----
    // wave owns n-tiles nt0,nt0+1 x m-tiles 0,1. SINGLE acc set (64 regs),
    // unroll 2 (max 2 ks of fragments live) -> no spill at cap 128.
    vf16 a00, a01, a10, a11;
    {
        const int nt0 = wid * 2;
        a00 = vzero16(); a01 = vzero16(); a10 = vzero16(); a11 = vzero16();
        #pragma unroll 2
        for (int ks = 0; ks < 32; ++ks) {
            const int k0 = ks * 16;
            vhalf8 ah0 = ld_act32(A, lane, 1024, 0,  k0);
            vhalf8 ah1 = ld_act32(A, lane, 1024, 32, k0);
            vhalf8 b0  = ld_pack(P1, nt0 * 32 + ks, lane);
            vhalf8 b1  = ld_pack(P1, (nt0 + 1) * 32 + ks, lane);
            a00 = MFMA32(ah0, b0, a00);
            a01 = MFMA32(ah0, b1, a01);
            a10 = MFMA32(ah1, b0, a10);
            a11 = MFMA32(ah1, b1, a11);
        }
    }
    __syncthreads();   // B2a: all waves done reading A
    {
        const int e0 = wid * 64;
        #pragma unroll
        for (int r = 0; r < 16; ++r) {
            const int rr = (r & 3) + 8 * (r >> 2) + 4 * (lane >> 5);
            st_hi(A, rr,      e0 + (lane & 31),      1024, gelu_fast(a00[r]));
            st_hi(A, rr,      e0 + 32 + (lane & 31), 1024, gelu_fast(a01[r]));
            st_hi(A, rr + 32, e0 + (lane & 31),      1024, gelu_fast(a10[r]));
            st_hi(A, rr + 32, e0 + 32 + (lane & 31), 1024, gelu_fast(a11[r]));
        }
    }
    __syncthreads();   // B2b: X1 ready (in A's region)

    // ---- GEMM2: X2 = gelu(X1 @ W_l1^T), 64x256, K=512, 32x32x16 ----
    vf16 c0, c1;
    {
        c0 = vzero16(); c1 = vzero16();
        #pragma unroll 2
        for (int ks = 0; ks < 32; ++ks) {
            const int k0 = ks * 16;
            vhalf8 ah0 = ld_act32(A, lane, 1024, 0,  k0);
            vhalf8 ah1 = ld_act32(A, lane, 1024, 32, k0);
            vhalf8 b   = ld_pack(P2, wid * 32 + ks, lane);
            c0 = MFMA32(ah0, b, c0);
            c1 = MFMA32(ah1, b, c1);
        }
    }
    __syncthreads();   // B3a: all waves done reading X1
    {
        const int e0 = wid * 32;
        #pragma unroll
        for (int r = 0; r < 16; ++r) {
            const int rr = (r & 3) + 8 * (r >> 2) + 4 * (lane >> 5);
            st_hi(A, rr,      e0 + (lane & 31), 512, gelu_fast(c0[r]));
            st_hi(A, rr + 32, e0 + (lane & 31), 512, gelu_fast(c1[r]));
        }
    }
    __syncthreads();   // B3b: X2 ready (in [0,32K))

    // ---- GEMM3: X3 = gelu(X2 @ W_l2^T), 64x128, K=256, 16x16x32 ----
    {
        const int e0 = wid * 16;               // wave owns n-tile wid
        vf4 ac[4];                             // m-tiles: rows 16*mt..16*mt+15
        #pragma unroll
        for (int mt = 0; mt < 4; ++mt) ac[mt] = vzero4();
        #pragma unroll 2
        for (int ks = 0; ks < 8; ++ks) {
            const int k0 = ks * 32;
            vhalf8 b = ld_pack(P3, wid * 8 + ks, lane);
            #pragma unroll
            for (int mt = 0; mt < 4; ++mt) {
                vhalf8 ah = ld_act16(A, lane, 512, mt * 16, k0);
                ac[mt] = MFMA16(ah, b, ac[mt]);
            }
        }
        __syncthreads();   // B4a: all waves done reading X2
        #pragma unroll
        for (int mt = 0; mt < 4; ++mt)
            #pragma unroll
            for (int r = 0; r < 4; ++r) {
                const int rr = mt * 16 + ((lane >> 4) << 2) + r;
                sX3[rr * 132 + e0 + (lane & 15)] = gelu_fast(ac[mt][r]);
            }
    }
    __syncthreads();   // B4b: X3 ready

    // ---- layer4 (fp32) + decision + flag: 64 rows x 8 lanes ----
    {
        const int row = tid >> 3;
        const int j   = tid & 7;
        float p = 0.0f;
        #pragma unroll
        for (int t = 0; t < 16; ++t)
            p = fmaf(sX3[row * 132 + j + 8 * t], W_l3[j + 8 * t], p);
        p += __shfl_down(p, 4, 8);
        p += __shfl_down(p, 2, 8);
        p += __shfl_down(p, 1, 8);
        if (j == 0) {
            const float prob = 1.0f / (1.0f + expf(-p));
            const float v    = prob * prev_m[row0 + row];
            const float st   = (v > 0.5f) ? 1.0f : 0.0f;
            const float cm   = st + 1e-10f;
            sM[row] = cm;
            mask_out[row0 + row]  = st;
            currm_out[row0 + row] = cm;
            if (fabsf(v - 0.5f) < BAND) {
                const unsigned int slot = atomicAdd(ctr, 1u);
                list[slot] = row0 + row;
            }
        }
    }
    __syncthreads();   // B5: sM ready

    // ---- epilogue: out = input * curr_m (re-read; L3-resident) ----
    #pragma unroll 4
    for (int it = 0; it < 16; ++it) {
        const int c = it * NT + tid;           // 8192 float4 = 64 rows x 128
        const int r = c >> 7;
        const int q = (c & 127) << 2;
        const float m = sM[r];
        const float4 v = *(const float4*)&input[(size_t)(row0 + r) * D0 + q];
        float4 o;
        o.x = v.x * m; o.y = v.y * m; o.z = v.z * m; o.w = v.w * m;
        *(float4*)&out[(size_t)(row0 + r) * D0 + q] = o;
    }
}

// ---------------- pass C: exact fp32 recompute, 2 columns/thread ------------
// (byte-identical to R13's measured fix pass)
__global__ __launch_bounds__(512) void fix_rows(
    const float* __restrict__ input, const float* __restrict__ prev_m,
    const float* __restrict__ WT1, const float* __restrict__ WT2,
    const float* __restrict__ WT3, const float* __restrict__ W_l3,
    const unsigned int* __restrict__ ctr, const int* __restrict__ list,
    float* __restrict__ out, float* __restrict__ mask_out, float* __restrict__ currm_out)
{
    __shared__ float sx[16][512];
    __shared__ float s1[16][512];
    __shared__ float s2[16][256];
    __shared__ float s3[16][128];
    __shared__ float scm[16];
    const int tid = threadIdx.x;
    const int n = (int)*ctr;

    for (int base = blockIdx.x * 16; base < n; base += gridDim.x * 16) {
        int cnt = n - base;
        if (cnt > 16) cnt = 16;
        __syncthreads();                       // protect prev iteration LDS
        #pragma unroll
        for (int g = 0; g < 16; ++g) {
            sx[g][tid] = (g < cnt) ? input[(size_t)list[base + g] * 512 + tid]
                                   : 0.0f;
        }
        __syncthreads();
        // L1: e in {tid&255, +256}; rows g0..g0+7 (g0 = (tid>>8)*8)
        {
            const int e = tid & 255, g0 = (tid >> 8) * 8;
            float a0[8], a1[8];
            #pragma unroll
            for (int g = 0; g < 8; ++g) { a0[g] = 0.0f; a1[g] = 0.0f; }
            #pragma unroll 2
            for (int kq = 0; kq < 128; ++kq) {
                const float u0 = WT1[(kq * 4 + 0) * 512 + e];
                const float u1 = WT1[(kq * 4 + 1) * 512 + e];
                const float u2 = WT1[(kq * 4 + 2) * 512 + e];
                const float u3 = WT1[(kq * 4 + 3) * 512 + e];
                const float v0 = WT1[(kq * 4 + 0) * 512 + e + 256];
                const float v1 = WT1[(kq * 4 + 1) * 512 + e + 256];
                const float v2 = WT1[(kq * 4 + 2) * 512 + e + 256];
                const float v3 = WT1[(kq * 4 + 3) * 512 + e + 256];
                #pragma unroll
                for (int g = 0; g < 8; ++g) {
                    const float4 xv = *(const float4*)&sx[g0 + g][kq * 4];
                    a0[g] = fmaf(xv.x, u0, a0[g]); a0[g] = fmaf(xv.y, u1, a0[g]);
                    a0[g] = fmaf(xv.z, u2, a0[g]); a0[g] = fmaf(xv.w, u3, a0[g]);
                    a1[g] = fmaf(xv.x, v0, a1[g]); a1[g] = fmaf(xv.y, v1, a1[g]);
                    a1[g] = fmaf(xv.z, v2, a1[g]); a1[g] = fmaf(xv.w, v3, a1[g]);
                }
            }
            #pragma unroll
            for (int g = 0; g < 8; ++g) {
                s1[g0 + g][e]       = gelu_exact(a0[g]);
                s1[g0 + g][e + 256] = gelu_exact(a1[g]);
            }
        }
        __syncthreads();
        // L2: e in {tid&127, +128}; rows g0..g0+3 (g0 = (tid>>7)*4)
        {
            const int e = tid & 127, g0 = (tid >> 7) * 4;
            float a0[4], a1[4];
            #pragma unroll
            for (int g = 0; g < 4; ++g) { a0[g] = 0.0f; a1[g] = 0.0f; }
            #pragma unroll 2
            for (int kq = 0; kq < 128; ++kq) {
                const float u0 = WT2[(kq * 4 + 0) * 256 + e];
                const float u1 = WT2[(kq * 4 + 1) * 256 + e];
                const float u2 = WT2[(kq * 4 + 2) * 256 + e];
                const float u3 = WT2[(kq * 4 + 3) * 256 + e];
                const float v0 = WT2[(kq * 4 + 0) * 256 + e + 128];
                const float v1 = WT2[(kq * 4 + 1) * 256 + e + 128];
                const float v2 = WT2[(kq * 4 + 2) * 256 + e + 128];
                const float v3 = WT2[(kq * 4 + 3) * 256 + e + 128];
                #pragma unroll
                for (int g = 0; g < 4; ++g) {
                    const float4 xv = *(const float4*)&s1[g0 + g][kq * 4];
                    a0[g] = fmaf(xv.x, u0, a0[g]); a0[g] = fmaf(xv.y, u1, a0[g]);
                    a0[g] = fmaf(xv.z, u2, a0[g]); a0[g] = fmaf(xv.w, u3, a0[g]);
                    a1[g] = fmaf(xv.x, v0, a1[g]); a1[g] = fmaf(xv.y, v1, a1[g]);
                    a1[g] = fmaf(xv.z, v2, a1[g]); a1[g] = fmaf(xv.w, v3, a1[g]);
                }
            }
            #pragma unroll
            for (int g = 0; g < 4; ++g) {
                s2[g0 + g][e]       = gelu_exact(a0[g]);
                s2[g0 + g][e + 128] = gelu_exact(a1[g]);
            }
        }
        __syncthreads();
        // L3: e in {tid&63, +64}; rows g0..g0+1 (g0 = (tid>>6)*2)
        {
            const int e = tid & 63, g0 = (tid >> 6) * 2;
            float a0[2], a1[2];
            #pragma unroll
            for (int g = 0; g < 2; ++g) { a0[g] = 0.0f; a1[g] = 0.0f; }
            #pragma unroll 2
            for (int kq = 0; kq < 64; ++kq) {
                const float u0 = WT3[(kq * 4 + 0) * 128 + e];
                const float u1 = WT3[(kq * 4 + 1) * 128 + e];
                const float u2 = WT3[(kq * 4 + 2) * 128 + e];
                const float u3 = WT3[(kq * 4 + 3) * 128 + e];
                const float v0 = WT3[(kq * 4 + 0) * 128 + e + 64];
                const float v1 = WT3[(kq * 4 + 1) * 128 + e + 64];
                const float v2 = WT3[(kq * 4 + 2) * 128 + e + 64];
                const float v3 = WT3[(kq * 4 + 3) * 128 + e + 64];
                #pragma unroll
                for (int g = 0; g < 2; ++g) {
                    const float4 xv = *(const float4*)&s2[g0 + g][kq * 4];
                    a0[g] = fmaf(xv.x, u0, a0[g]); a0[g] = fmaf(xv.y, u1, a0[g]);
                    a0[g] = fmaf(xv.z, u2, a0[g]); a0[g] = fmaf(xv.w, u3, a0[g]);
                    a1[g] = fmaf(xv.x, v0, a1[g]); a1[g] = fmaf(xv.y, v1, a1[g]);
                    a1[g] = fmaf(xv.z, v2, a1[g]); a1[g] = fmaf(xv.w, v3, a1[g]);
                }
            }
            #pragma unroll
            for (int g = 0; g < 2; ++g) {
                s3[g0 + g][e]      = gelu_exact(a0[g]);
                s3[g0 + g][e + 64] = gelu_exact(a1[g]);
            }
        }
        __syncthreads();
        // L4 + decision: 16 rows x 16 lanes (tid < 256)
        if (tid < 256) {
            const int g = tid >> 4, j = tid & 15;
            float p = 0.0f;
            #pragma unroll
            for (int t = 0; t < 8; ++t)
                p = fmaf(s3[g][j + 16 * t], W_l3[j + 16 * t], p);
            #pragma unroll
            for (int off = 8; off > 0; off >>= 1)
                p += __shfl_down(p, off, 16);
            if (j == 0 && g < cnt) {
                const int row = list[base + g];
                const float prob = 1.0f / (1.0f + expf(-p));
                const float v    = prob * prev_m[row];
                const float st   = (v > 0.5f) ? 1.0f : 0.0f;
                const float cm   = st + 1e-10f;
                mask_out[row]  = st;
                currm_out[row] = cm;
                scm[g] = cm;
            }
        }
        __syncthreads();
        // rewrite out rows
        for (int idx = tid; idx < cnt * 128; idx += 512) {
            const int g = idx >> 7;
            const int q = (idx & 127) << 2;
            const int row = list[base + g];
            const float cm = scm[g];
            const float4 v = *(const float4*)&input[(size_t)row * 512 + q];
            float4 o;
            o.x = v.x * cm; o.y = v.y * cm; o.z = v.z * cm; o.w = v.w * cm;
            *(float4*)&out[(size_t)row * 512 + q] = o;
        }
    }
}

}  // namespace

extern "C" void kernel_launch(void* const* d_in, const int* in_sizes, int n_in,
                              void* d_out, int out_size, void* d_ws, size_t ws_size,
                              hipStream_t stream) {
    const float* input  = (const float*)d_in[0];
    // d_in[1] = attention_mask: unused by the reference computation
    const float* prev_m = (const float*)d_in[2];
    const float* W_L    = (const float*)d_in[3];
    const float* W_l1   = (const float*)d_in[4];
    const float* W_l2   = (const float*)d_in[5];
    const float* W_l3   = (const float*)d_in[6];

    float* out_p   = (float*)d_out;                  // [R, 512]
    float* mask_p  = out_p + (size_t)R_ROWS * D0;    // [R]
    float* currm_p = mask_p + R_ROWS;                // [R]

    // workspace (bytes): ctr @0, list @1024 (256KB), packed fp16 weights,
    // then fp32 transposed weights for the fix pass.
    char* ws = (char*)d_ws;
    unsigned int* ctr = (unsigned int*)ws;
    int* list = (int*)(ws + 1024);
    char* P1 = ws + 263168;                 // 512 KB
    char* P2 = ws + 787456;                 // 256 KB
    char* P3 = ws + 1049600;                // 64 KB
    float* WT1 = (float*)(ws + 1115136);    // 1 MB
    float* WT2 = (float*)(ws + 2163712);    // 512 KB
    float* WT3 = (float*)(ws + 2688000);    // 128 KB
    // total ws use: 2819072 bytes

    (void)hipMemsetAsync(ctr, 0, sizeof(unsigned int), stream);
    prep_weights<<<1872, 256, 0, stream>>>(W_L, W_l1, W_l2, P1, P2, P3,
                                           WT1, WT2, WT3);
    mlp_mfma<<<R_ROWS / TM, NT, 0, stream>>>(input, prev_m, W_l3,
                                             P1, P2, P3,
                                             out_p, mask_p, currm_p, ctr, list);
    fix_rows<<<512, 512, 0, stream>>>(input, prev_m, WT1, WT2, WT3, W_l3,
                                      ctr, list, out_p, mask_p, currm_p);
}